// Round 9
// baseline (796.779 us; speedup 1.0000x reference)
//
#include <hip/hip_runtime.h>
#include <math.h>

#define N_NODES 50000
#define N_EDGES 600000
#define HDIM 128
#define NCLS 10
#define NGRAPH 500
#define BN_EPS 1e-5f
#define SCAN_BLOCKS 196  // ceil(N_NODES/256)

typedef short bf16x8 __attribute__((ext_vector_type(8)));
typedef float f32x4 __attribute__((ext_vector_type(4)));

// ---------------------------------------------------------------------------
// Column stats: stats[0..127] += column sums, stats[128..255] += column sumsq
// ---------------------------------------------------------------------------
__global__ void colstats_kernel(const float* __restrict__ X, int M, float* __restrict__ stats) {
    int col = threadIdx.x & 127;
    int sub = threadIdx.x >> 7;
    float s = 0.f, sq = 0.f;
    for (int r = blockIdx.x * 2 + sub; r < M; r += gridDim.x * 2) {
        float v = X[(size_t)r * HDIM + col];
        s += v; sq += v * v;
    }
    atomicAdd(&stats[col], s);
    atomicAdd(&stats[HDIM + col], sq);
}

// ---------------------------------------------------------------------------
// CSR build: histogram over dst, 3-level multiblock exclusive scan, scatter
// ---------------------------------------------------------------------------
__global__ void hist_kernel(const int* __restrict__ ei, int* __restrict__ counts) {
    int e = blockIdx.x * 256 + threadIdx.x;
    if (e < N_EDGES) atomicAdd(&counts[ei[N_EDGES + e]], 1);
}

__global__ __launch_bounds__(256) void scan1_kernel(const int* __restrict__ counts,
                                                    int* __restrict__ partial,
                                                    int* __restrict__ blockSums) {
    __shared__ int tmp[256];
    int tid = threadIdx.x;
    int i = blockIdx.x * 256 + tid;
    int v = (i < N_NODES) ? counts[i] : 0;
    tmp[tid] = v;
    __syncthreads();
#pragma unroll
    for (int off = 1; off < 256; off <<= 1) {
        int t = (tid >= off) ? tmp[tid - off] : 0;
        __syncthreads();
        tmp[tid] += t;
        __syncthreads();
    }
    if (i < N_NODES) partial[i] = tmp[tid] - v;
    if (tid == 255) blockSums[blockIdx.x] = tmp[255];
}

__global__ __launch_bounds__(256) void scan2_kernel(const int* __restrict__ blockSums,
                                                    int* __restrict__ blockBase) {
    __shared__ int tmp[256];
    int tid = threadIdx.x;
    int v = (tid < SCAN_BLOCKS) ? blockSums[tid] : 0;
    tmp[tid] = v;
    __syncthreads();
#pragma unroll
    for (int off = 1; off < 256; off <<= 1) {
        int t = (tid >= off) ? tmp[tid - off] : 0;
        __syncthreads();
        tmp[tid] += t;
        __syncthreads();
    }
    if (tid < SCAN_BLOCKS) blockBase[tid] = tmp[tid] - v;
}

__global__ __launch_bounds__(256) void scan3_kernel(const int* __restrict__ partial,
                                                    const int* __restrict__ blockBase,
                                                    int* __restrict__ offsets,
                                                    int* __restrict__ cursor) {
    int i = blockIdx.x * 256 + threadIdx.x;
    if (i < N_NODES) {
        int o = partial[i] + blockBase[blockIdx.x];
        offsets[i] = o;
        cursor[i] = o;
    }
    if (i == 0) offsets[N_NODES] = N_EDGES;
}

__global__ void fill_kernel(const int* __restrict__ ei, int* __restrict__ cursor, int* __restrict__ csr) {
    int e = blockIdx.x * 256 + threadIdx.x;
    if (e < N_EDGES) {
        int d = ei[N_EDGES + e];
        int pos = atomicAdd(&cursor[d], 1);
        csr[pos] = ei[e];
    }
}

// ---------------------------------------------------------------------------
// GIN aggregation (unchanged): z[n] = h[n] + sum_{src->n} h[src]
// ---------------------------------------------------------------------------
__global__ __launch_bounds__(256) void agg_kernel(const float* __restrict__ h,
                                                  const int* __restrict__ offsets,
                                                  const int* __restrict__ csr,
                                                  float* __restrict__ z) {
    int node = (blockIdx.x * 256 + threadIdx.x) >> 6;
    int lane = threadIdx.x & 63;
    if (node >= N_NODES) return;
    int c0 = lane * 2;
    int beg = offsets[node], end = offsets[node + 1];
    const float2 self = *(const float2*)&h[(size_t)node * HDIM + c0];
    float ax = self.x, ay = self.y;
    for (int j = beg; j < end; j += 64) {
        int cnt = min(64, end - j);
        int sl = (j + lane < end) ? csr[j + lane] : 0;
        int t = 0;
        for (; t + 4 <= cnt; t += 4) {
            int s0 = __shfl(sl, t, 64);
            int s1 = __shfl(sl, t + 1, 64);
            int s2 = __shfl(sl, t + 2, 64);
            int s3 = __shfl(sl, t + 3, 64);
            float2 v0 = *(const float2*)&h[(size_t)s0 * HDIM + c0];
            float2 v1 = *(const float2*)&h[(size_t)s1 * HDIM + c0];
            float2 v2 = *(const float2*)&h[(size_t)s2 * HDIM + c0];
            float2 v3 = *(const float2*)&h[(size_t)s3 * HDIM + c0];
            ax += v0.x + v1.x + v2.x + v3.x;
            ay += v0.y + v1.y + v2.y + v3.y;
        }
        for (; t < cnt; t++) {
            int s = __shfl(sl, t, 64);
            float2 hv = *(const float2*)&h[(size_t)s * HDIM + c0];
            ax += hv.x; ay += hv.y;
        }
    }
    float2 o; o.x = ax; o.y = ay;
    *(float2*)&z[(size_t)node * HDIM + c0] = o;
}

// ---------------------------------------------------------------------------
// segment_sum (unchanged): sorted batch -> per-graph direct reduce
// ---------------------------------------------------------------------------
__global__ __launch_bounds__(128) void segsum2_kernel(const float* __restrict__ h,
                                                      const int* __restrict__ batch,
                                                      float* __restrict__ g) {
    int b = blockIdx.x;
    int tid = threadIdx.x;
    __shared__ int bounds[2];
    if (tid < 2) {
        int target = b + tid;
        int lo = 0, hi = N_NODES;
        while (lo < hi) {
            int mid = (lo + hi) >> 1;
            if (batch[mid] < target) lo = mid + 1; else hi = mid;
        }
        bounds[tid] = lo;
    }
    __syncthreads();
    int beg = bounds[0], end = bounds[1];
    float s = 0.f;
    for (int r = beg; r < end; r++) s += h[(size_t)r * HDIM + tid];
    g[b * HDIM + tid] = s;
}

// ---------------------------------------------------------------------------
// Weight prep, FRAG-MAJOR layout: flat index i = ((s*8+c)*64 + l)*8 + j where
// s=K-step, c=col-tile, l=lane(q=l>>4,c16=l&15), j=frag elem. Value =
// W[k][n] with n = c*16+c16, k = s*32+q*8+j. GEMM lane l then reads its 16B
// frag for tile t at (t*64+l)*8 shorts — a wave's read is 1KB contiguous.
// ---------------------------------------------------------------------------
__device__ inline void dekker_split(float v, unsigned short& hi, unsigned short& lo) {
    unsigned u = __float_as_uint(v);
    hi = (unsigned short)(u >> 16);
    float flo = v - __uint_as_float(u & 0xffff0000u);
    lo = (unsigned short)(__float_as_uint(flo) >> 16);
}

__device__ inline void fragmajor_decode(int i, int& k, int& n) {
    int j = i & 7, l = (i >> 3) & 63, c = (i >> 9) & 7, s = (i >> 12) & 3;
    n = c * 16 + (l & 15);
    k = s * 32 + (l >> 4) * 8 + j;
}

__global__ __launch_bounds__(256) void prep_w(const float* __restrict__ W1,
                                              const float* __restrict__ W2,
                                              unsigned short* __restrict__ wh,
                                              unsigned short* __restrict__ wl) {
    int m = blockIdx.x;  // 0..5
    const float* src = (m < 3) ? (W1 + m * HDIM * HDIM) : (W2 + (m - 3) * HDIM * HDIM);
    unsigned short* dh = wh + m * HDIM * HDIM;
    unsigned short* dl = wl + m * HDIM * HDIM;
    for (int i = threadIdx.x; i < HDIM * HDIM; i += 256) {
        int k, n;
        fragmajor_decode(i, k, n);
        unsigned short h16, l16;
        dekker_split(src[k * HDIM + n], h16, l16);
        dh[i] = h16; dl[i] = l16;
    }
}

__global__ __launch_bounds__(256) void prep_feat(const float* __restrict__ W,
                                                 const float* __restrict__ bfeat,
                                                 const float* __restrict__ stats,
                                                 const float* __restrict__ gamma,
                                                 const float* __restrict__ beta,
                                                 float invCnt,
                                                 unsigned short* __restrict__ dh,
                                                 unsigned short* __restrict__ dl,
                                                 float* __restrict__ biasF) {
    __shared__ float aP[HDIM], bP[HDIM];
    int tid = threadIdx.x;
    if (tid < HDIM) {
        float m = stats[tid] * invCnt;
        float v = stats[HDIM + tid] * invCnt - m * m;
        float a = gamma[tid] * rsqrtf(v + BN_EPS);
        aP[tid] = a;
        bP[tid] = beta[tid] - m * a;
    }
    __syncthreads();
    for (int i = tid; i < HDIM * HDIM; i += 256) {
        int k, n;
        fragmajor_decode(i, k, n);
        unsigned short h16, l16;
        dekker_split(aP[k] * W[k * HDIM + n], h16, l16);
        dh[i] = h16; dl[i] = l16;
    }
    if (tid < HDIM) {
        float acc = bfeat[tid];
        for (int k = 0; k < HDIM; k++) acc = fmaf(bP[k], W[k * HDIM + tid], acc);
        biasF[tid] = acc;
    }
}

// ---------------------------------------------------------------------------
// MFMA GEMM v3 (latency-hiding): C[M,128] = op(A)[M,128] @ B[128,128] + bias.
// bf16 Dekker 3-term (AhBh + AlBh + AhBl), fp32 accumulate — numerics
// identical to R5 kernel (same term/accumulation order).
// MODE 0: plain A, RELU.  MODE 1: plain A, no relu, +STATS, in-place safe.
// MODE 2: A gets BN+relu in-register (params from 1KB LDS table).
// Block = 64 rows, 4 waves; wave w owns rows [bid*64+w*16, +16) x 128 cols.
// Latency plan: all 8 A-loads issued in prologue; B frag-pairs stream through
// a 4-deep ring buffer (8 loads in flight); 32 fully-unrolled (s,c) tiles,
// 3 MFMA each. Grid 782 (~3 blk/CU) + <=128 VGPR target -> ~12 waves/CU.
// ---------------------------------------------------------------------------
template <int MODE>
__global__ __launch_bounds__(256, 4) void mfma_gemm(const float* __restrict__ A,
                                                    const unsigned short* __restrict__ Bh,
                                                    const unsigned short* __restrict__ Bl,
                                                    const float* __restrict__ bias,
                                                    float* __restrict__ C, int M,
                                                    const float* __restrict__ statsPre,
                                                    const float* __restrict__ gammaPre,
                                                    const float* __restrict__ betaPre,
                                                    float invCnt,
                                                    float* __restrict__ statsOut) {
    __shared__ float sA[HDIM], sB[HDIM];  // MODE 2 BN params (1KB)
    const int tid = threadIdx.x;
    const int w = tid >> 6, l = tid & 63;
    const int q = l >> 4, c16 = l & 15;
    const int rb = blockIdx.x * 64 + w * 16;

    if (MODE == 2) {
        if (tid < HDIM) {
            float m = statsPre[tid] * invCnt;
            float var = statsPre[HDIM + tid] * invCnt - m * m;
            float a = gammaPre[tid] * rsqrtf(var + BN_EPS);
            sA[tid] = a;
            sB[tid] = betaPre[tid] - m * a;
        }
        __syncthreads();
    }

    // prologue: issue ALL A loads (8 independent float4). Also guarantees all
    // in-place (C==A) reads precede any write.
    const int rowA = min(rb + c16, M - 1);
    const float* ap = A + (size_t)rowA * HDIM + q * 8;
    float4 araw[4][2];
#pragma unroll
    for (int s = 0; s < 4; s++) {
        araw[s][0] = *(const float4*)(ap + s * 32);
        araw[s][1] = *(const float4*)(ap + s * 32 + 4);
    }

    // B frag ring buffer, depth 4 (8 loads in flight)
    const unsigned short* bhp = Bh + (size_t)l * 8;
    const unsigned short* blp = Bl + (size_t)l * 8;
    bf16x8 bhBuf[4], blBuf[4];
#pragma unroll
    for (int t = 0; t < 4; t++) {
        bhBuf[t] = *(const bf16x8*)(bhp + (size_t)t * 512);
        blBuf[t] = *(const bf16x8*)(blp + (size_t)t * 512);
    }

    f32x4 acc[8];
#pragma unroll
    for (int c = 0; c < 8; c++) acc[c] = (f32x4){0.f, 0.f, 0.f, 0.f};

    bf16x8 ah, al;
#pragma unroll
    for (int t = 0; t < 32; t++) {
        const int s = t >> 3, c = t & 7, b = t & 3;
        if (c == 0) {
            // convert this s-step's A frag (waits only on araw[s])
            const int k0 = s * 32 + q * 8;
            float vv[8] = {araw[s][0].x, araw[s][0].y, araw[s][0].z, araw[s][0].w,
                           araw[s][1].x, araw[s][1].y, araw[s][1].z, araw[s][1].w};
            float aK[8], bK[8];
            if (MODE == 2) {
                float4 a0 = *(const float4*)&sA[k0];
                float4 a1 = *(const float4*)&sA[k0 + 4];
                float4 b0 = *(const float4*)&sB[k0];
                float4 b1 = *(const float4*)&sB[k0 + 4];
                aK[0] = a0.x; aK[1] = a0.y; aK[2] = a0.z; aK[3] = a0.w;
                aK[4] = a1.x; aK[5] = a1.y; aK[6] = a1.z; aK[7] = a1.w;
                bK[0] = b0.x; bK[1] = b0.y; bK[2] = b0.z; bK[3] = b0.w;
                bK[4] = b1.x; bK[5] = b1.y; bK[6] = b1.z; bK[7] = b1.w;
            }
#pragma unroll
            for (int j = 0; j < 8; j++) {
                float v = vv[j];
                if (MODE == 2) v = fmaxf(fmaf(v, aK[j], bK[j]), 0.f);
                unsigned u = __float_as_uint(v);
                ah[j] = (short)(u >> 16);
                float flo = v - __uint_as_float(u & 0xffff0000u);
                al[j] = (short)(__float_as_uint(flo) >> 16);
            }
        }
        f32x4 a0 = __builtin_amdgcn_mfma_f32_16x16x32_bf16(ah, bhBuf[b], acc[c], 0, 0, 0);
        a0 = __builtin_amdgcn_mfma_f32_16x16x32_bf16(al, bhBuf[b], a0, 0, 0, 0);
        a0 = __builtin_amdgcn_mfma_f32_16x16x32_bf16(ah, blBuf[b], a0, 0, 0, 0);
        acc[c] = a0;
        if (t < 28) {  // refill ring slot just consumed
            bhBuf[b] = *(const bf16x8*)(bhp + (size_t)(t + 4) * 512);
            blBuf[b] = *(const bf16x8*)(blp + (size_t)(t + 4) * 512);
        }
    }

    // epilogue: bias (+relu) (+stats), scalar stores (row q*4+reg, col c*16+c16)
    float bsv[8];
#pragma unroll
    for (int c = 0; c < 8; c++) bsv[c] = bias[c * 16 + c16];
    float ssum[8], ssq[8];
    if (MODE == 1) {
#pragma unroll
        for (int c = 0; c < 8; c++) { ssum[c] = 0.f; ssq[c] = 0.f; }
    }
#pragma unroll
    for (int reg = 0; reg < 4; reg++) {
        int row = rb + q * 4 + reg;
        if (row < M) {
            float* cp = C + (size_t)row * HDIM + c16;
#pragma unroll
            for (int c = 0; c < 8; c++) {
                float v = acc[c][reg] + bsv[c];
                if (MODE != 1) v = fmaxf(v, 0.f);
                cp[c * 16] = v;
                if (MODE == 1) { ssum[c] += v; ssq[c] += v * v; }
            }
        }
    }
    if (MODE == 1) {
#pragma unroll
        for (int c = 0; c < 8; c++) {
            float s2 = ssum[c] + __shfl_xor(ssum[c], 16, 64);
            float s4 = s2 + __shfl_xor(s2, 32, 64);
            float t2 = ssq[c] + __shfl_xor(ssq[c], 16, 64);
            float t4 = t2 + __shfl_xor(t2, 32, 64);
            if (q == 0) {
                atomicAdd(&statsOut[c * 16 + c16], s4);
                atomicAdd(&statsOut[HDIM + c * 16 + c16], t4);
            }
        }
    }
}

// ---------------------------------------------------------------------------
// Small fp32 GEMM (kept for the 500-row FC block).
// ---------------------------------------------------------------------------
template <bool PRE_A, bool PRE_B, bool RELU, bool STATS>
__global__ __launch_bounds__(256, 3) void gemm_bn(const float* A, const float* __restrict__ B,
                                                  const float* __restrict__ bias, float* C, int M,
                                                  const float* __restrict__ statsPre,
                                                  const float* __restrict__ gammaPre,
                                                  const float* __restrict__ betaPre,
                                                  float invCnt, float* __restrict__ statsOut) {
    __shared__ float At[64][65];
    __shared__ float Bs[64][128];
    __shared__ float aPre[128], bPre[128];

    const int tid = threadIdx.x;
    const int tx = tid & 15, ty = tid >> 4;
    const int r0 = blockIdx.x * 64;

    if (PRE_A || PRE_B) {
        if (tid < 128) {
            float m = statsPre[tid] * invCnt;
            float v = statsPre[128 + tid] * invCnt - m * m;
            float a = gammaPre[tid] * rsqrtf(v + BN_EPS);
            aPre[tid] = a;
            bPre[tid] = betaPre[tid] - m * a;
        }
        __syncthreads();
    }

    float acc[4][8];
#pragma unroll
    for (int i = 0; i < 4; i++)
#pragma unroll
        for (int j = 0; j < 8; j++) acc[i][j] = 0.f;

    float biasEff[8];
#pragma unroll
    for (int j = 0; j < 8; j++) biasEff[j] = bias[8 * tx + j];
    if (PRE_B) {
        for (int k = 0; k < 128; k++) {
            float bb = bPre[k];
            const float* Brow = B + (size_t)k * HDIM + 8 * tx;
#pragma unroll
            for (int j = 0; j < 8; j++) biasEff[j] = fmaf(bb, Brow[j], biasEff[j]);
        }
    }

    for (int kc = 0; kc < 128; kc += 64) {
#pragma unroll
        for (int i = 0; i < 4; i++) {
            int f4 = tid + i * 256;
            int row = f4 >> 4;
            int kg = f4 & 15;
            int grow = r0 + row;
            float4 av;
            if (grow < M) av = *(const float4*)(A + (size_t)grow * HDIM + kc + kg * 4);
            else av = make_float4(0.f, 0.f, 0.f, 0.f);
            if (PRE_A) {
                int kb = kc + kg * 4;
                av.x = fmaxf(fmaf(av.x, aPre[kb + 0], bPre[kb + 0]), 0.f);
                av.y = fmaxf(fmaf(av.y, aPre[kb + 1], bPre[kb + 1]), 0.f);
                av.z = fmaxf(fmaf(av.z, aPre[kb + 2], bPre[kb + 2]), 0.f);
                av.w = fmaxf(fmaf(av.w, aPre[kb + 3], bPre[kb + 3]), 0.f);
            }
            At[kg * 4 + 0][row] = av.x;
            At[kg * 4 + 1][row] = av.y;
            At[kg * 4 + 2][row] = av.z;
            At[kg * 4 + 3][row] = av.w;
        }
#pragma unroll
        for (int i = 0; i < 8; i++) {
            int f4 = tid + i * 256;
            int krow = f4 >> 5;
            int cg = f4 & 31;
            float4 bv = *(const float4*)(B + (size_t)(kc + krow) * HDIM + cg * 4);
            if (PRE_B) {
                float s = aPre[kc + krow];
                bv.x *= s; bv.y *= s; bv.z *= s; bv.w *= s;
            }
            *(float4*)&Bs[krow][cg * 4] = bv;
        }
        __syncthreads();
#pragma unroll 8
        for (int k = 0; k < 64; k++) {
            float av[4];
            av[0] = At[k][ty];
            av[1] = At[k][ty + 16];
            av[2] = At[k][ty + 32];
            av[3] = At[k][ty + 48];
            const float4 b0 = *(const float4*)&Bs[k][8 * tx];
            const float4 b1 = *(const float4*)&Bs[k][8 * tx + 4];
            float bv[8] = {b0.x, b0.y, b0.z, b0.w, b1.x, b1.y, b1.z, b1.w};
#pragma unroll
            for (int i = 0; i < 4; i++)
#pragma unroll
                for (int j = 0; j < 8; j++) acc[i][j] = fmaf(av[i], bv[j], acc[i][j]);
        }
        __syncthreads();
    }

    float s[8], sq[8];
    if (STATS) {
#pragma unroll
        for (int j = 0; j < 8; j++) { s[j] = 0.f; sq[j] = 0.f; }
    }
#pragma unroll
    for (int i = 0; i < 4; i++) {
        int grow = r0 + ty + 16 * i;
        if (grow < M) {
            float v[8];
#pragma unroll
            for (int j = 0; j < 8; j++) {
                v[j] = acc[i][j] + biasEff[j];
                if (RELU) v[j] = fmaxf(v[j], 0.f);
                if (STATS) { s[j] += v[j]; sq[j] += v[j] * v[j]; }
            }
            float4 o0 = make_float4(v[0], v[1], v[2], v[3]);
            float4 o1 = make_float4(v[4], v[5], v[6], v[7]);
            *(float4*)(C + (size_t)grow * HDIM + 8 * tx) = o0;
            *(float4*)(C + (size_t)grow * HDIM + 8 * tx + 4) = o1;
        }
    }
    if (STATS) {
        float* red = &At[0][0];
#pragma unroll
        for (int j = 0; j < 8; j++) {
            red[ty * 128 + 8 * tx + j] = s[j];
            red[2048 + ty * 128 + 8 * tx + j] = sq[j];
        }
        __syncthreads();
        if (tid < 128) {
            float t = 0.f;
#pragma unroll
            for (int u = 0; u < 16; u++) t += red[u * 128 + tid];
            atomicAdd(&statsOut[tid], t);
        } else {
            int col = tid - 128;
            float t = 0.f;
#pragma unroll
            for (int u = 0; u < 16; u++) t += red[2048 + u * 128 + col];
            atomicAdd(&statsOut[128 + col], t);
        }
    }
}

// ---------------------------------------------------------------------------
// Head: logits = BN(g2)@W_cls + b_cls (BN folded), then log_softmax.
// ---------------------------------------------------------------------------
__global__ __launch_bounds__(256) void head_kernel(const float* __restrict__ g2,
                                                   const float* __restrict__ stats,
                                                   const float* __restrict__ gamma,
                                                   const float* __restrict__ beta,
                                                   const float* __restrict__ Wc,
                                                   const float* __restrict__ bc,
                                                   float* __restrict__ out, float invCnt) {
    __shared__ float Wf[HDIM * NCLS];
    __shared__ float bf[NCLS];
    __shared__ float aP[HDIM], bP[HDIM];
    const int tid = threadIdx.x;
    if (tid < HDIM) {
        float m = stats[tid] * invCnt;
        float v = stats[HDIM + tid] * invCnt - m * m;
        float a = gamma[tid] * rsqrtf(v + BN_EPS);
        aP[tid] = a;
        bP[tid] = beta[tid] - m * a;
    }
    __syncthreads();
    for (int idx = tid; idx < HDIM * NCLS; idx += 256) {
        int k = idx / NCLS;
        Wf[idx] = aP[k] * Wc[idx];
    }
    if (tid < NCLS) {
        float sv = bc[tid];
        for (int k = 0; k < HDIM; k++) sv = fmaf(bP[k], Wc[k * NCLS + tid], sv);
        bf[tid] = sv;
    }
    __syncthreads();
    int row = blockIdx.x * 256 + tid;
    if (row >= NGRAPH) return;
    float l[NCLS];
#pragma unroll
    for (int c = 0; c < NCLS; c++) l[c] = bf[c];
    for (int k = 0; k < HDIM; k++) {
        float gv = g2[row * HDIM + k];
#pragma unroll
        for (int c = 0; c < NCLS; c++) l[c] = fmaf(gv, Wf[k * NCLS + c], l[c]);
    }
    float mx = l[0];
#pragma unroll
    for (int c = 1; c < NCLS; c++) mx = fmaxf(mx, l[c]);
    float se = 0.f;
#pragma unroll
    for (int c = 0; c < NCLS; c++) se += expf(l[c] - mx);
    float lse = mx + logf(se);
#pragma unroll
    for (int c = 0; c < NCLS; c++) out[row * NCLS + c] = l[c] - lse;
}

// ---------------------------------------------------------------------------
extern "C" void kernel_launch(void* const* d_in, const int* in_sizes, int n_in,
                              void* d_out, int out_size, void* d_ws, size_t ws_size,
                              hipStream_t stream) {
    const float* x          = (const float*)d_in[0];
    const int*   ei         = (const int*)d_in[1];
    const int*   batch      = (const int*)d_in[2];
    const float* gamma_feat = (const float*)d_in[3];
    const float* beta_feat  = (const float*)d_in[4];
    const float* W_feat     = (const float*)d_in[5];
    const float* b_feat     = (const float*)d_in[6];
    const float* gin_W1     = (const float*)d_in[7];
    const float* gin_b1     = (const float*)d_in[8];
    const float* gin_gamma  = (const float*)d_in[9];
    const float* gin_beta   = (const float*)d_in[10];
    const float* gin_W2     = (const float*)d_in[11];
    const float* gin_b2     = (const float*)d_in[12];
    const float* gamma_fc   = (const float*)d_in[13];
    const float* beta_fc    = (const float*)d_in[14];
    const float* W_fc       = (const float*)d_in[15];
    const float* b_fc       = (const float*)d_in[16];
    const float* gamma_h    = (const float*)d_in[17];
    const float* beta_h     = (const float*)d_in[18];
    const float* W_cls      = (const float*)d_in[19];
    const float* b_cls      = (const float*)d_in[20];
    float* out = (float*)d_out;

    float* ws = (float*)d_ws;
    size_t off = 0;
    float* h  = ws + off; off += (size_t)N_NODES * HDIM;
    float* zy = ws + off; off += (size_t)N_NODES * HDIM;   // z and y alias (per-wave-band in-place gemm)
    float* g2 = ws + off; off += NGRAPH * HDIM;
    float* g  = ws + off; off += NGRAPH * HDIM;            // fully written by segsum2
    size_t zstart = off;                                    // ---- zeroed region ----
    float* stats = ws + off; off += 256 * 6;
    int* counts = (int*)(ws + off); off += N_NODES;
    size_t zbytes = (off - zstart) * sizeof(float);         // ---- end zeroed ----
    int* offsets   = (int*)(ws + off); off += N_NODES + 1;
    int* cursor    = (int*)(ws + off); off += N_NODES;
    int* csr       = (int*)(ws + off); off += N_EDGES;
    int* partial   = (int*)(ws + off); off += N_NODES;
    int* blockSums = (int*)(ws + off); off += 256;
    int* blockBase = (int*)(ws + off); off += 256;
    off = (off + 3) & ~(size_t)3;                           // 16B-align weight arrays
    unsigned short* wt_hi = (unsigned short*)(ws + off); off += 7 * HDIM * HDIM / 2;
    unsigned short* wt_lo = (unsigned short*)(ws + off); off += 7 * HDIM * HDIM / 2;
    float* biasF = ws + off; off += HDIM;

    float* statsX  = stats;
    float* statsYa[3] = {stats + 256, stats + 512, stats + 768};
    float* statsG  = stats + 1024;
    float* statsG2 = stats + 1280;

    hipMemsetAsync(stats, 0, zbytes, stream);

    const float invN = 1.f / (float)N_NODES;
    const float invG = 1.f / (float)NGRAPH;
    const int eblocks = (N_EDGES + 255) / 256;        // 2344
    const int nwaves  = (N_NODES * 64 + 255) / 256;   // 12500
    const int mblocks = (N_NODES + 63) / 64;          // 782

    // GIN weight prep (no deps) + BN(x) stats + CSR build
    prep_w<<<6, 256, 0, stream>>>(gin_W1, gin_W2, wt_hi, wt_lo);
    colstats_kernel<<<256, 256, 0, stream>>>(x, N_NODES, statsX);
    hist_kernel<<<eblocks, 256, 0, stream>>>(ei, counts);
    scan1_kernel<<<SCAN_BLOCKS, 256, 0, stream>>>(counts, partial, blockSums);
    scan2_kernel<<<1, 256, 0, stream>>>(blockSums, blockBase);
    scan3_kernel<<<SCAN_BLOCKS, 256, 0, stream>>>(partial, blockBase, offsets, cursor);
    fill_kernel<<<eblocks, 256, 0, stream>>>(ei, cursor, csr);
    prep_feat<<<1, 256, 0, stream>>>(W_feat, b_feat, statsX, gamma_feat, beta_feat, invN,
                                     wt_hi + 6 * HDIM * HDIM, wt_lo + 6 * HDIM * HDIM, biasF);

    // h = relu(BN(x) @ W_feat + b_feat)   [BN folded into prepped B]
    mfma_gemm<0><<<mblocks, 256, 0, stream>>>(
        x, wt_hi + 6 * HDIM * HDIM, wt_lo + 6 * HDIM * HDIM, biasF, h, N_NODES,
        nullptr, nullptr, nullptr, invN, nullptr);

    for (int i = 0; i < 3; i++) {
        // z = h + sum_neighbors h
        agg_kernel<<<nwaves, 256, 0, stream>>>(h, offsets, csr, zy);
        // y = z @ W1 + b1   (in-place, + column stats of y)
        mfma_gemm<1><<<mblocks, 256, 0, stream>>>(
            zy, wt_hi + i * HDIM * HDIM, wt_lo + i * HDIM * HDIM, gin_b1 + i * HDIM,
            zy, N_NODES, nullptr, nullptr, nullptr, invN, statsYa[i]);
        // h = relu( relu(BN(y)) @ W2 + b2 )   [BN+relu in-register on A frags]
        mfma_gemm<2><<<mblocks, 256, 0, stream>>>(
            zy, wt_hi + (3 + i) * HDIM * HDIM, wt_lo + (3 + i) * HDIM * HDIM, gin_b2 + i * HDIM,
            h, N_NODES, statsYa[i], gin_gamma + i * HDIM, gin_beta + i * HDIM, invN, nullptr);
    }

    // g = segment_sum(h, batch)  (sorted batch -> direct per-graph reduce)
    segsum2_kernel<<<NGRAPH, 128, 0, stream>>>(h, batch, g);
    colstats_kernel<<<8, 256, 0, stream>>>(g, NGRAPH, statsG);
    // g2 = relu(BN(g) @ W_fc + b_fc) + stats of g2
    gemm_bn<false, true, true, true><<<(NGRAPH + 63) / 64, 256, 0, stream>>>(
        g, W_fc, b_fc, g2, NGRAPH, statsG, gamma_fc, beta_fc, invG, statsG2);
    // logits = BN(g2) @ W_cls + b_cls -> log_softmax
    head_kernel<<<2, 256, 0, stream>>>(g2, statsG2, gamma_h, beta_h, W_cls, b_cls, out, invG);
}

// Round 11
// 756.943 us; speedup vs baseline: 1.0526x; 1.0526x over previous
//
#include <hip/hip_runtime.h>
#include <math.h>

#define N_NODES 50000
#define N_EDGES 600000
#define HDIM 128
#define NCLS 10
#define NGRAPH 500
#define BN_EPS 1e-5f
#define SCAN_BLOCKS 196  // ceil(N_NODES/256)

typedef short bf16x8 __attribute__((ext_vector_type(8)));
typedef float f32x4 __attribute__((ext_vector_type(4)));

// ---------------------------------------------------------------------------
// Column stats: stats[0..127] += column sums, stats[128..255] += column sumsq
// ---------------------------------------------------------------------------
__global__ void colstats_kernel(const float* __restrict__ X, int M, float* __restrict__ stats) {
    int col = threadIdx.x & 127;
    int sub = threadIdx.x >> 7;
    float s = 0.f, sq = 0.f;
    for (int r = blockIdx.x * 2 + sub; r < M; r += gridDim.x * 2) {
        float v = X[(size_t)r * HDIM + col];
        s += v; sq += v * v;
    }
    atomicAdd(&stats[col], s);
    atomicAdd(&stats[HDIM + col], sq);
}

// ---------------------------------------------------------------------------
// CSR build: histogram over dst, 3-level multiblock exclusive scan, scatter
// ---------------------------------------------------------------------------
__global__ void hist_kernel(const int* __restrict__ ei, int* __restrict__ counts) {
    int e = blockIdx.x * 256 + threadIdx.x;
    if (e < N_EDGES) atomicAdd(&counts[ei[N_EDGES + e]], 1);
}

__global__ __launch_bounds__(256) void scan1_kernel(const int* __restrict__ counts,
                                                    int* __restrict__ partial,
                                                    int* __restrict__ blockSums) {
    __shared__ int tmp[256];
    int tid = threadIdx.x;
    int i = blockIdx.x * 256 + tid;
    int v = (i < N_NODES) ? counts[i] : 0;
    tmp[tid] = v;
    __syncthreads();
#pragma unroll
    for (int off = 1; off < 256; off <<= 1) {
        int t = (tid >= off) ? tmp[tid - off] : 0;
        __syncthreads();
        tmp[tid] += t;
        __syncthreads();
    }
    if (i < N_NODES) partial[i] = tmp[tid] - v;
    if (tid == 255) blockSums[blockIdx.x] = tmp[255];
}

__global__ __launch_bounds__(256) void scan2_kernel(const int* __restrict__ blockSums,
                                                    int* __restrict__ blockBase) {
    __shared__ int tmp[256];
    int tid = threadIdx.x;
    int v = (tid < SCAN_BLOCKS) ? blockSums[tid] : 0;
    tmp[tid] = v;
    __syncthreads();
#pragma unroll
    for (int off = 1; off < 256; off <<= 1) {
        int t = (tid >= off) ? tmp[tid - off] : 0;
        __syncthreads();
        tmp[tid] += t;
        __syncthreads();
    }
    if (tid < SCAN_BLOCKS) blockBase[tid] = tmp[tid] - v;
}

__global__ __launch_bounds__(256) void scan3_kernel(const int* __restrict__ partial,
                                                    const int* __restrict__ blockBase,
                                                    int* __restrict__ offsets,
                                                    int* __restrict__ cursor) {
    int i = blockIdx.x * 256 + threadIdx.x;
    if (i < N_NODES) {
        int o = partial[i] + blockBase[blockIdx.x];
        offsets[i] = o;
        cursor[i] = o;
    }
    if (i == 0) offsets[N_NODES] = N_EDGES;
}

__global__ void fill_kernel(const int* __restrict__ ei, int* __restrict__ cursor, int* __restrict__ csr) {
    int e = blockIdx.x * 256 + threadIdx.x;
    if (e < N_EDGES) {
        int d = ei[N_EDGES + e];
        int pos = atomicAdd(&cursor[d], 1);
        csr[pos] = ei[e];
    }
}

// ---------------------------------------------------------------------------
// GIN aggregation (unchanged): z[n] = h[n] + sum_{src->n} h[src]
// ---------------------------------------------------------------------------
__global__ __launch_bounds__(256) void agg_kernel(const float* __restrict__ h,
                                                  const int* __restrict__ offsets,
                                                  const int* __restrict__ csr,
                                                  float* __restrict__ z) {
    int node = (blockIdx.x * 256 + threadIdx.x) >> 6;
    int lane = threadIdx.x & 63;
    if (node >= N_NODES) return;
    int c0 = lane * 2;
    int beg = offsets[node], end = offsets[node + 1];
    const float2 self = *(const float2*)&h[(size_t)node * HDIM + c0];
    float ax = self.x, ay = self.y;
    for (int j = beg; j < end; j += 64) {
        int cnt = min(64, end - j);
        int sl = (j + lane < end) ? csr[j + lane] : 0;
        int t = 0;
        for (; t + 4 <= cnt; t += 4) {
            int s0 = __shfl(sl, t, 64);
            int s1 = __shfl(sl, t + 1, 64);
            int s2 = __shfl(sl, t + 2, 64);
            int s3 = __shfl(sl, t + 3, 64);
            float2 v0 = *(const float2*)&h[(size_t)s0 * HDIM + c0];
            float2 v1 = *(const float2*)&h[(size_t)s1 * HDIM + c0];
            float2 v2 = *(const float2*)&h[(size_t)s2 * HDIM + c0];
            float2 v3 = *(const float2*)&h[(size_t)s3 * HDIM + c0];
            ax += v0.x + v1.x + v2.x + v3.x;
            ay += v0.y + v1.y + v2.y + v3.y;
        }
        for (; t < cnt; t++) {
            int s = __shfl(sl, t, 64);
            float2 hv = *(const float2*)&h[(size_t)s * HDIM + c0];
            ax += hv.x; ay += hv.y;
        }
    }
    float2 o; o.x = ax; o.y = ay;
    *(float2*)&z[(size_t)node * HDIM + c0] = o;
}

// ---------------------------------------------------------------------------
// segment_sum (unchanged): sorted batch -> per-graph direct reduce
// ---------------------------------------------------------------------------
__global__ __launch_bounds__(128) void segsum2_kernel(const float* __restrict__ h,
                                                      const int* __restrict__ batch,
                                                      float* __restrict__ g) {
    int b = blockIdx.x;
    int tid = threadIdx.x;
    __shared__ int bounds[2];
    if (tid < 2) {
        int target = b + tid;
        int lo = 0, hi = N_NODES;
        while (lo < hi) {
            int mid = (lo + hi) >> 1;
            if (batch[mid] < target) lo = mid + 1; else hi = mid;
        }
        bounds[tid] = lo;
    }
    __syncthreads();
    int beg = bounds[0], end = bounds[1];
    float s = 0.f;
    for (int r = beg; r < end; r++) s += h[(size_t)r * HDIM + tid];
    g[b * HDIM + tid] = s;
}

// ---------------------------------------------------------------------------
// Weight prep, FRAG-MAJOR layout: flat index i = ((s*8+c)*64 + l)*8 + j where
// s=K-step, c=col-tile, l=lane(q=l>>4,c16=l&15), j=frag elem. Value =
// W[k][n] with n = c*16+c16, k = s*32+q*8+j. This layout is LINEAR in the
// order the GEMM consumes it -> LDS staging is a straight memcpy.
// ---------------------------------------------------------------------------
__device__ inline void dekker_split(float v, unsigned short& hi, unsigned short& lo) {
    unsigned u = __float_as_uint(v);
    hi = (unsigned short)(u >> 16);
    float flo = v - __uint_as_float(u & 0xffff0000u);
    lo = (unsigned short)(__float_as_uint(flo) >> 16);
}

__device__ inline void fragmajor_decode(int i, int& k, int& n) {
    int j = i & 7, l = (i >> 3) & 63, c = (i >> 9) & 7, s = (i >> 12) & 3;
    n = c * 16 + (l & 15);
    k = s * 32 + (l >> 4) * 8 + j;
}

__global__ __launch_bounds__(256) void prep_w(const float* __restrict__ W1,
                                              const float* __restrict__ W2,
                                              unsigned short* __restrict__ wh,
                                              unsigned short* __restrict__ wl) {
    int m = blockIdx.x;  // 0..5
    const float* src = (m < 3) ? (W1 + m * HDIM * HDIM) : (W2 + (m - 3) * HDIM * HDIM);
    unsigned short* dh = wh + m * HDIM * HDIM;
    unsigned short* dl = wl + m * HDIM * HDIM;
    for (int i = threadIdx.x; i < HDIM * HDIM; i += 256) {
        int k, n;
        fragmajor_decode(i, k, n);
        unsigned short h16, l16;
        dekker_split(src[k * HDIM + n], h16, l16);
        dh[i] = h16; dl[i] = l16;
    }
}

__global__ __launch_bounds__(256) void prep_feat(const float* __restrict__ W,
                                                 const float* __restrict__ bfeat,
                                                 const float* __restrict__ stats,
                                                 const float* __restrict__ gamma,
                                                 const float* __restrict__ beta,
                                                 float invCnt,
                                                 unsigned short* __restrict__ dh,
                                                 unsigned short* __restrict__ dl,
                                                 float* __restrict__ biasF) {
    __shared__ float aP[HDIM], bP[HDIM];
    int tid = threadIdx.x;
    if (tid < HDIM) {
        float m = stats[tid] * invCnt;
        float v = stats[HDIM + tid] * invCnt - m * m;
        float a = gamma[tid] * rsqrtf(v + BN_EPS);
        aP[tid] = a;
        bP[tid] = beta[tid] - m * a;
    }
    __syncthreads();
    for (int i = tid; i < HDIM * HDIM; i += 256) {
        int k, n;
        fragmajor_decode(i, k, n);
        unsigned short h16, l16;
        dekker_split(aP[k] * W[k * HDIM + n], h16, l16);
        dh[i] = h16; dl[i] = l16;
    }
    if (tid < HDIM) {
        float acc = bfeat[tid];
        for (int k = 0; k < HDIM; k++) acc = fmaf(bP[k], W[k * HDIM + tid], acc);
        biasF[tid] = acc;
    }
}

// ---------------------------------------------------------------------------
// MFMA GEMM v4 (LDS-B, m97-style): C[M,128] = op(A)[M,128] @ B[128,128]+bias.
// bf16 Dekker 3-term (AhBh + AlBh + AhBl), fp32 accumulate — same numerics
// as R7 (same term/accumulation order).
// Structure per R9 post-mortem: the no-LDS register ring was demoted to
// scratch by the compiler under launch_bounds(256,4) (VGPR_Count=44). v4
// stages all of B (hi+lo, 64KB frag-major = linear copy) into LDS once per
// block; tiles then consume 2x ds_read_b128 + 3 MFMA. launch_bounds(256,2)
// gives a 256-VGPR budget so araw/acc stay in registers. LDS (65KB) limits
// occupancy to 2 blocks/CU = 8 waves; LDS latency (~120cyc) is coverable.
// MODE 0: plain A, RELU.  MODE 1: plain A, no relu, +STATS, in-place safe.
// MODE 2: A gets BN+relu in-register (params from LDS table).
// ---------------------------------------------------------------------------
template <int MODE>
__global__ __launch_bounds__(256, 2) void mfma_gemm(const float* __restrict__ A,
                                                    const unsigned short* __restrict__ Bh,
                                                    const unsigned short* __restrict__ Bl,
                                                    const float* __restrict__ bias,
                                                    float* __restrict__ C, int M,
                                                    const float* __restrict__ statsPre,
                                                    const float* __restrict__ gammaPre,
                                                    const float* __restrict__ betaPre,
                                                    float invCnt,
                                                    float* __restrict__ statsOut) {
    __shared__ unsigned short sBfrag[32768];  // [0,16384): hi, [16384,32768): lo
    __shared__ float sA[HDIM], sBp[HDIM];     // MODE 2 BN params
    const int tid = threadIdx.x;
    const int w = tid >> 6, l = tid & 63;
    const int q = l >> 4, c16 = l & 15;
    const int rb = blockIdx.x * 64 + w * 16;

    // prologue: issue all 8 A float4 loads (also: in-place reads precede writes)
    const int rowA = min(rb + c16, M - 1);
    const float* ap = A + (size_t)rowA * HDIM + q * 8;
    float4 araw[4][2];
#pragma unroll
    for (int s = 0; s < 4; s++) {
        araw[s][0] = *(const float4*)(ap + s * 32);
        araw[s][1] = *(const float4*)(ap + s * 32 + 4);
    }

    // stage B hi+lo into LDS (linear copy: frag-major is consumption order)
    {
        const float4* gh = (const float4*)Bh;   // 2048 float4 = 32KB
        const float4* gl = (const float4*)Bl;
        float4* sh = (float4*)sBfrag;
#pragma unroll
        for (int i = 0; i < 8; i++) sh[tid + i * 256] = gh[tid + i * 256];
#pragma unroll
        for (int i = 0; i < 8; i++) sh[2048 + tid + i * 256] = gl[tid + i * 256];
    }
    if (MODE == 2) {
        if (tid < HDIM) {
            float m = statsPre[tid] * invCnt;
            float var = statsPre[HDIM + tid] * invCnt - m * m;
            float a = gammaPre[tid] * rsqrtf(var + BN_EPS);
            sA[tid] = a;
            sBp[tid] = betaPre[tid] - m * a;
        }
    }
    __syncthreads();

    f32x4 acc[8];
#pragma unroll
    for (int c = 0; c < 8; c++) acc[c] = (f32x4){0.f, 0.f, 0.f, 0.f};

#pragma unroll
    for (int s = 0; s < 4; s++) {
        // convert this s-step's A frag
        const int k0 = s * 32 + q * 8;
        float vv[8] = {araw[s][0].x, araw[s][0].y, araw[s][0].z, araw[s][0].w,
                       araw[s][1].x, araw[s][1].y, araw[s][1].z, araw[s][1].w};
        bf16x8 ah, al;
#pragma unroll
        for (int j = 0; j < 8; j++) {
            float v = vv[j];
            if (MODE == 2) v = fmaxf(fmaf(v, sA[k0 + j], sBp[k0 + j]), 0.f);
            unsigned u = __float_as_uint(v);
            ah[j] = (short)(u >> 16);
            float flo = v - __uint_as_float(u & 0xffff0000u);
            al[j] = (short)(__float_as_uint(flo) >> 16);
        }
#pragma unroll
        for (int c = 0; c < 8; c++) {
            const int t = s * 8 + c;
            const int fo = (t * 64 + l) * 8;
            bf16x8 bh = *(const bf16x8*)&sBfrag[fo];
            bf16x8 bl = *(const bf16x8*)&sBfrag[16384 + fo];
            f32x4 a0 = __builtin_amdgcn_mfma_f32_16x16x32_bf16(ah, bh, acc[c], 0, 0, 0);
            a0 = __builtin_amdgcn_mfma_f32_16x16x32_bf16(al, bh, a0, 0, 0, 0);
            a0 = __builtin_amdgcn_mfma_f32_16x16x32_bf16(ah, bl, a0, 0, 0, 0);
            acc[c] = a0;
        }
    }

    // epilogue: bias (+relu) (+stats)
    float bsv[8];
#pragma unroll
    for (int c = 0; c < 8; c++) bsv[c] = bias[c * 16 + c16];
    float ssum[8], ssq[8];
    if (MODE == 1) {
#pragma unroll
        for (int c = 0; c < 8; c++) { ssum[c] = 0.f; ssq[c] = 0.f; }
    }
#pragma unroll
    for (int reg = 0; reg < 4; reg++) {
        int row = rb + q * 4 + reg;
        if (row < M) {
            float* cp = C + (size_t)row * HDIM + c16;
#pragma unroll
            for (int c = 0; c < 8; c++) {
                float v = acc[c][reg] + bsv[c];
                if (MODE != 1) v = fmaxf(v, 0.f);
                cp[c * 16] = v;
                if (MODE == 1) { ssum[c] += v; ssq[c] += v * v; }
            }
        }
    }
    if (MODE == 1) {
#pragma unroll
        for (int c = 0; c < 8; c++) {
            float s2 = ssum[c] + __shfl_xor(ssum[c], 16, 64);
            float s4 = s2 + __shfl_xor(s2, 32, 64);
            float t2 = ssq[c] + __shfl_xor(ssq[c], 16, 64);
            float t4 = t2 + __shfl_xor(t2, 32, 64);
            if (q == 0) {
                atomicAdd(&statsOut[c * 16 + c16], s4);
                atomicAdd(&statsOut[HDIM + c * 16 + c16], t4);
            }
        }
    }
}

// ---------------------------------------------------------------------------
// Small fp32 GEMM (kept for the 500-row FC block).
// ---------------------------------------------------------------------------
template <bool PRE_A, bool PRE_B, bool RELU, bool STATS>
__global__ __launch_bounds__(256, 3) void gemm_bn(const float* A, const float* __restrict__ B,
                                                  const float* __restrict__ bias, float* C, int M,
                                                  const float* __restrict__ statsPre,
                                                  const float* __restrict__ gammaPre,
                                                  const float* __restrict__ betaPre,
                                                  float invCnt, float* __restrict__ statsOut) {
    __shared__ float At[64][65];
    __shared__ float Bs[64][128];
    __shared__ float aPre[128], bPre[128];

    const int tid = threadIdx.x;
    const int tx = tid & 15, ty = tid >> 4;
    const int r0 = blockIdx.x * 64;

    if (PRE_A || PRE_B) {
        if (tid < 128) {
            float m = statsPre[tid] * invCnt;
            float v = statsPre[128 + tid] * invCnt - m * m;
            float a = gammaPre[tid] * rsqrtf(v + BN_EPS);
            aPre[tid] = a;
            bPre[tid] = betaPre[tid] - m * a;
        }
        __syncthreads();
    }

    float acc[4][8];
#pragma unroll
    for (int i = 0; i < 4; i++)
#pragma unroll
        for (int j = 0; j < 8; j++) acc[i][j] = 0.f;

    float biasEff[8];
#pragma unroll
    for (int j = 0; j < 8; j++) biasEff[j] = bias[8 * tx + j];
    if (PRE_B) {
        for (int k = 0; k < 128; k++) {
            float bb = bPre[k];
            const float* Brow = B + (size_t)k * HDIM + 8 * tx;
#pragma unroll
            for (int j = 0; j < 8; j++) biasEff[j] = fmaf(bb, Brow[j], biasEff[j]);
        }
    }

    for (int kc = 0; kc < 128; kc += 64) {
#pragma unroll
        for (int i = 0; i < 4; i++) {
            int f4 = tid + i * 256;
            int row = f4 >> 4;
            int kg = f4 & 15;
            int grow = r0 + row;
            float4 av;
            if (grow < M) av = *(const float4*)(A + (size_t)grow * HDIM + kc + kg * 4);
            else av = make_float4(0.f, 0.f, 0.f, 0.f);
            if (PRE_A) {
                int kb = kc + kg * 4;
                av.x = fmaxf(fmaf(av.x, aPre[kb + 0], bPre[kb + 0]), 0.f);
                av.y = fmaxf(fmaf(av.y, aPre[kb + 1], bPre[kb + 1]), 0.f);
                av.z = fmaxf(fmaf(av.z, aPre[kb + 2], bPre[kb + 2]), 0.f);
                av.w = fmaxf(fmaf(av.w, aPre[kb + 3], bPre[kb + 3]), 0.f);
            }
            At[kg * 4 + 0][row] = av.x;
            At[kg * 4 + 1][row] = av.y;
            At[kg * 4 + 2][row] = av.z;
            At[kg * 4 + 3][row] = av.w;
        }
#pragma unroll
        for (int i = 0; i < 8; i++) {
            int f4 = tid + i * 256;
            int krow = f4 >> 5;
            int cg = f4 & 31;
            float4 bv = *(const float4*)(B + (size_t)(kc + krow) * HDIM + cg * 4);
            if (PRE_B) {
                float s = aPre[kc + krow];
                bv.x *= s; bv.y *= s; bv.z *= s; bv.w *= s;
            }
            *(float4*)&Bs[krow][cg * 4] = bv;
        }
        __syncthreads();
#pragma unroll 8
        for (int k = 0; k < 64; k++) {
            float av[4];
            av[0] = At[k][ty];
            av[1] = At[k][ty + 16];
            av[2] = At[k][ty + 32];
            av[3] = At[k][ty + 48];
            const float4 b0 = *(const float4*)&Bs[k][8 * tx];
            const float4 b1 = *(const float4*)&Bs[k][8 * tx + 4];
            float bv[8] = {b0.x, b0.y, b0.z, b0.w, b1.x, b1.y, b1.z, b1.w};
#pragma unroll
            for (int i = 0; i < 4; i++)
#pragma unroll
                for (int j = 0; j < 8; j++) acc[i][j] = fmaf(av[i], bv[j], acc[i][j]);
        }
        __syncthreads();
    }

    float s[8], sq[8];
    if (STATS) {
#pragma unroll
        for (int j = 0; j < 8; j++) { s[j] = 0.f; sq[j] = 0.f; }
    }
#pragma unroll
    for (int i = 0; i < 4; i++) {
        int grow = r0 + ty + 16 * i;
        if (grow < M) {
            float v[8];
#pragma unroll
            for (int j = 0; j < 8; j++) {
                v[j] = acc[i][j] + biasEff[j];
                if (RELU) v[j] = fmaxf(v[j], 0.f);
                if (STATS) { s[j] += v[j]; sq[j] += v[j] * v[j]; }
            }
            float4 o0 = make_float4(v[0], v[1], v[2], v[3]);
            float4 o1 = make_float4(v[4], v[5], v[6], v[7]);
            *(float4*)(C + (size_t)grow * HDIM + 8 * tx) = o0;
            *(float4*)(C + (size_t)grow * HDIM + 8 * tx + 4) = o1;
        }
    }
    if (STATS) {
        float* red = &At[0][0];
#pragma unroll
        for (int j = 0; j < 8; j++) {
            red[ty * 128 + 8 * tx + j] = s[j];
            red[2048 + ty * 128 + 8 * tx + j] = sq[j];
        }
        __syncthreads();
        if (tid < 128) {
            float t = 0.f;
#pragma unroll
            for (int u = 0; u < 16; u++) t += red[u * 128 + tid];
            atomicAdd(&statsOut[tid], t);
        } else {
            int col = tid - 128;
            float t = 0.f;
#pragma unroll
            for (int u = 0; u < 16; u++) t += red[2048 + u * 128 + col];
            atomicAdd(&statsOut[128 + col], t);
        }
    }
}

// ---------------------------------------------------------------------------
// Head: logits = BN(g2)@W_cls + b_cls (BN folded), then log_softmax.
// ---------------------------------------------------------------------------
__global__ __launch_bounds__(256) void head_kernel(const float* __restrict__ g2,
                                                   const float* __restrict__ stats,
                                                   const float* __restrict__ gamma,
                                                   const float* __restrict__ beta,
                                                   const float* __restrict__ Wc,
                                                   const float* __restrict__ bc,
                                                   float* __restrict__ out, float invCnt) {
    __shared__ float Wf[HDIM * NCLS];
    __shared__ float bf[NCLS];
    __shared__ float aP[HDIM], bP[HDIM];
    const int tid = threadIdx.x;
    if (tid < HDIM) {
        float m = stats[tid] * invCnt;
        float v = stats[HDIM + tid] * invCnt - m * m;
        float a = gamma[tid] * rsqrtf(v + BN_EPS);
        aP[tid] = a;
        bP[tid] = beta[tid] - m * a;
    }
    __syncthreads();
    for (int idx = tid; idx < HDIM * NCLS; idx += 256) {
        int k = idx / NCLS;
        Wf[idx] = aP[k] * Wc[idx];
    }
    if (tid < NCLS) {
        float sv = bc[tid];
        for (int k = 0; k < HDIM; k++) sv = fmaf(bP[k], Wc[k * NCLS + tid], sv);
        bf[tid] = sv;
    }
    __syncthreads();
    int row = blockIdx.x * 256 + tid;
    if (row >= NGRAPH) return;
    float l[NCLS];
#pragma unroll
    for (int c = 0; c < NCLS; c++) l[c] = bf[c];
    for (int k = 0; k < HDIM; k++) {
        float gv = g2[row * HDIM + k];
#pragma unroll
        for (int c = 0; c < NCLS; c++) l[c] = fmaf(gv, Wf[k * NCLS + c], l[c]);
    }
    float mx = l[0];
#pragma unroll
    for (int c = 1; c < NCLS; c++) mx = fmaxf(mx, l[c]);
    float se = 0.f;
#pragma unroll
    for (int c = 0; c < NCLS; c++) se += expf(l[c] - mx);
    float lse = mx + logf(se);
#pragma unroll
    for (int c = 0; c < NCLS; c++) out[row * NCLS + c] = l[c] - lse;
}

// ---------------------------------------------------------------------------
extern "C" void kernel_launch(void* const* d_in, const int* in_sizes, int n_in,
                              void* d_out, int out_size, void* d_ws, size_t ws_size,
                              hipStream_t stream) {
    const float* x          = (const float*)d_in[0];
    const int*   ei         = (const int*)d_in[1];
    const int*   batch      = (const int*)d_in[2];
    const float* gamma_feat = (const float*)d_in[3];
    const float* beta_feat  = (const float*)d_in[4];
    const float* W_feat     = (const float*)d_in[5];
    const float* b_feat     = (const float*)d_in[6];
    const float* gin_W1     = (const float*)d_in[7];
    const float* gin_b1     = (const float*)d_in[8];
    const float* gin_gamma  = (const float*)d_in[9];
    const float* gin_beta   = (const float*)d_in[10];
    const float* gin_W2     = (const float*)d_in[11];
    const float* gin_b2     = (const float*)d_in[12];
    const float* gamma_fc   = (const float*)d_in[13];
    const float* beta_fc    = (const float*)d_in[14];
    const float* W_fc       = (const float*)d_in[15];
    const float* b_fc       = (const float*)d_in[16];
    const float* gamma_h    = (const float*)d_in[17];
    const float* beta_h     = (const float*)d_in[18];
    const float* W_cls      = (const float*)d_in[19];
    const float* b_cls      = (const float*)d_in[20];
    float* out = (float*)d_out;

    float* ws = (float*)d_ws;
    size_t off = 0;
    float* h  = ws + off; off += (size_t)N_NODES * HDIM;
    float* zy = ws + off; off += (size_t)N_NODES * HDIM;   // z and y alias (per-wave-band in-place gemm)
    float* g2 = ws + off; off += NGRAPH * HDIM;
    float* g  = ws + off; off += NGRAPH * HDIM;            // fully written by segsum2
    size_t zstart = off;                                    // ---- zeroed region ----
    float* stats = ws + off; off += 256 * 6;
    int* counts = (int*)(ws + off); off += N_NODES;
    size_t zbytes = (off - zstart) * sizeof(float);         // ---- end zeroed ----
    int* offsets   = (int*)(ws + off); off += N_NODES + 1;
    int* cursor    = (int*)(ws + off); off += N_NODES;
    int* csr       = (int*)(ws + off); off += N_EDGES;
    int* partial   = (int*)(ws + off); off += N_NODES;
    int* blockSums = (int*)(ws + off); off += 256;
    int* blockBase = (int*)(ws + off); off += 256;
    off = (off + 3) & ~(size_t)3;                           // 16B-align weight arrays
    unsigned short* wt_hi = (unsigned short*)(ws + off); off += 7 * HDIM * HDIM / 2;
    unsigned short* wt_lo = (unsigned short*)(ws + off); off += 7 * HDIM * HDIM / 2;
    float* biasF = ws + off; off += HDIM;

    float* statsX  = stats;
    float* statsYa[3] = {stats + 256, stats + 512, stats + 768};
    float* statsG  = stats + 1024;
    float* statsG2 = stats + 1280;

    hipMemsetAsync(stats, 0, zbytes, stream);

    const float invN = 1.f / (float)N_NODES;
    const float invG = 1.f / (float)NGRAPH;
    const int eblocks = (N_EDGES + 255) / 256;        // 2344
    const int nwaves  = (N_NODES * 64 + 255) / 256;   // 12500
    const int mblocks = (N_NODES + 63) / 64;          // 782

    // GIN weight prep (no deps) + BN(x) stats + CSR build
    prep_w<<<6, 256, 0, stream>>>(gin_W1, gin_W2, wt_hi, wt_lo);
    colstats_kernel<<<256, 256, 0, stream>>>(x, N_NODES, statsX);
    hist_kernel<<<eblocks, 256, 0, stream>>>(ei, counts);
    scan1_kernel<<<SCAN_BLOCKS, 256, 0, stream>>>(counts, partial, blockSums);
    scan2_kernel<<<1, 256, 0, stream>>>(blockSums, blockBase);
    scan3_kernel<<<SCAN_BLOCKS, 256, 0, stream>>>(partial, blockBase, offsets, cursor);
    fill_kernel<<<eblocks, 256, 0, stream>>>(ei, cursor, csr);
    prep_feat<<<1, 256, 0, stream>>>(W_feat, b_feat, statsX, gamma_feat, beta_feat, invN,
                                     wt_hi + 6 * HDIM * HDIM, wt_lo + 6 * HDIM * HDIM, biasF);

    // h = relu(BN(x) @ W_feat + b_feat)   [BN folded into prepped B]
    mfma_gemm<0><<<mblocks, 256, 0, stream>>>(
        x, wt_hi + 6 * HDIM * HDIM, wt_lo + 6 * HDIM * HDIM, biasF, h, N_NODES,
        nullptr, nullptr, nullptr, invN, nullptr);

    for (int i = 0; i < 3; i++) {
        // z = h + sum_neighbors h
        agg_kernel<<<nwaves, 256, 0, stream>>>(h, offsets, csr, zy);
        // y = z @ W1 + b1   (in-place, + column stats of y)
        mfma_gemm<1><<<mblocks, 256, 0, stream>>>(
            zy, wt_hi + i * HDIM * HDIM, wt_lo + i * HDIM * HDIM, gin_b1 + i * HDIM,
            zy, N_NODES, nullptr, nullptr, nullptr, invN, statsYa[i]);
        // h = relu( relu(BN(y)) @ W2 + b2 )   [BN+relu in-register on A frags]
        mfma_gemm<2><<<mblocks, 256, 0, stream>>>(
            zy, wt_hi + (3 + i) * HDIM * HDIM, wt_lo + (3 + i) * HDIM * HDIM, gin_b2 + i * HDIM,
            h, N_NODES, statsYa[i], gin_gamma + i * HDIM, gin_beta + i * HDIM, invN, nullptr);
    }

    // g = segment_sum(h, batch)  (sorted batch -> direct per-graph reduce)
    segsum2_kernel<<<NGRAPH, 128, 0, stream>>>(h, batch, g);
    colstats_kernel<<<8, 256, 0, stream>>>(g, NGRAPH, statsG);
    // g2 = relu(BN(g) @ W_fc + b_fc) + stats of g2
    gemm_bn<false, true, true, true><<<(NGRAPH + 63) / 64, 256, 0, stream>>>(
        g, W_fc, b_fc, g2, NGRAPH, statsG, gamma_fc, beta_fc, invG, statsG2);
    // logits = BN(g2) @ W_cls + b_cls -> log_softmax
    head_kernel<<<2, 256, 0, stream>>>(g2, statsG2, gamma_h, beta_h, W_cls, b_cls, out, invG);
}

// Round 14
// 623.619 us; speedup vs baseline: 1.2777x; 1.2138x over previous
//
#include <hip/hip_runtime.h>
#include <math.h>

#define N_NODES 50000
#define N_EDGES 600000
#define HDIM 128
#define NCLS 10
#define NGRAPH 500
#define BN_EPS 1e-5f
#define SCAN_BLOCKS 196  // ceil(N_NODES/256)
#define NTILES 3125      // N_NODES / 16
#define GBLK 512         // gemm grid: 2 blocks/CU
#define NITER 4          // ceil(NTILES / (GBLK*2))

typedef short bf16x8 __attribute__((ext_vector_type(8)));
typedef float f32x4 __attribute__((ext_vector_type(4)));

// ---------------------------------------------------------------------------
// Column stats: stats[0..127] += column sums, stats[128..255] += column sumsq
// ---------------------------------------------------------------------------
__global__ void colstats_kernel(const float* __restrict__ X, int M, float* __restrict__ stats) {
    int col = threadIdx.x & 127;
    int sub = threadIdx.x >> 7;
    float s = 0.f, sq = 0.f;
    for (int r = blockIdx.x * 2 + sub; r < M; r += gridDim.x * 2) {
        float v = X[(size_t)r * HDIM + col];
        s += v; sq += v * v;
    }
    atomicAdd(&stats[col], s);
    atomicAdd(&stats[HDIM + col], sq);
}

// ---------------------------------------------------------------------------
// CSR build: histogram over dst, 3-level multiblock exclusive scan, scatter
// ---------------------------------------------------------------------------
__global__ void hist_kernel(const int* __restrict__ ei, int* __restrict__ counts) {
    int e = blockIdx.x * 256 + threadIdx.x;
    if (e < N_EDGES) atomicAdd(&counts[ei[N_EDGES + e]], 1);
}

__global__ __launch_bounds__(256) void scan1_kernel(const int* __restrict__ counts,
                                                    int* __restrict__ partial,
                                                    int* __restrict__ blockSums) {
    __shared__ int tmp[256];
    int tid = threadIdx.x;
    int i = blockIdx.x * 256 + tid;
    int v = (i < N_NODES) ? counts[i] : 0;
    tmp[tid] = v;
    __syncthreads();
#pragma unroll
    for (int off = 1; off < 256; off <<= 1) {
        int t = (tid >= off) ? tmp[tid - off] : 0;
        __syncthreads();
        tmp[tid] += t;
        __syncthreads();
    }
    if (i < N_NODES) partial[i] = tmp[tid] - v;
    if (tid == 255) blockSums[blockIdx.x] = tmp[255];
}

__global__ __launch_bounds__(256) void scan2_kernel(const int* __restrict__ blockSums,
                                                    int* __restrict__ blockBase) {
    __shared__ int tmp[256];
    int tid = threadIdx.x;
    int v = (tid < SCAN_BLOCKS) ? blockSums[tid] : 0;
    tmp[tid] = v;
    __syncthreads();
#pragma unroll
    for (int off = 1; off < 256; off <<= 1) {
        int t = (tid >= off) ? tmp[tid - off] : 0;
        __syncthreads();
        tmp[tid] += t;
        __syncthreads();
    }
    if (tid < SCAN_BLOCKS) blockBase[tid] = tmp[tid] - v;
}

__global__ __launch_bounds__(256) void scan3_kernel(const int* __restrict__ partial,
                                                    const int* __restrict__ blockBase,
                                                    int* __restrict__ offsets,
                                                    int* __restrict__ cursor) {
    int i = blockIdx.x * 256 + threadIdx.x;
    if (i < N_NODES) {
        int o = partial[i] + blockBase[blockIdx.x];
        offsets[i] = o;
        cursor[i] = o;
    }
    if (i == 0) offsets[N_NODES] = N_EDGES;
}

__global__ void fill_kernel(const int* __restrict__ ei, int* __restrict__ cursor, int* __restrict__ csr) {
    int e = blockIdx.x * 256 + threadIdx.x;
    if (e < N_EDGES) {
        int d = ei[N_EDGES + e];
        int pos = atomicAdd(&cursor[d], 1);
        csr[pos] = ei[e];
    }
}

// ---------------------------------------------------------------------------
// GIN aggregation (unchanged): z[n] = h[n] + sum_{src->n} h[src]
// ---------------------------------------------------------------------------
__global__ __launch_bounds__(256) void agg_kernel(const float* __restrict__ h,
                                                  const int* __restrict__ offsets,
                                                  const int* __restrict__ csr,
                                                  float* __restrict__ z) {
    int node = (blockIdx.x * 256 + threadIdx.x) >> 6;
    int lane = threadIdx.x & 63;
    if (node >= N_NODES) return;
    int c0 = lane * 2;
    int beg = offsets[node], end = offsets[node + 1];
    const float2 self = *(const float2*)&h[(size_t)node * HDIM + c0];
    float ax = self.x, ay = self.y;
    for (int j = beg; j < end; j += 64) {
        int cnt = min(64, end - j);
        int sl = (j + lane < end) ? csr[j + lane] : 0;
        int t = 0;
        for (; t + 4 <= cnt; t += 4) {
            int s0 = __shfl(sl, t, 64);
            int s1 = __shfl(sl, t + 1, 64);
            int s2 = __shfl(sl, t + 2, 64);
            int s3 = __shfl(sl, t + 3, 64);
            float2 v0 = *(const float2*)&h[(size_t)s0 * HDIM + c0];
            float2 v1 = *(const float2*)&h[(size_t)s1 * HDIM + c0];
            float2 v2 = *(const float2*)&h[(size_t)s2 * HDIM + c0];
            float2 v3 = *(const float2*)&h[(size_t)s3 * HDIM + c0];
            ax += v0.x + v1.x + v2.x + v3.x;
            ay += v0.y + v1.y + v2.y + v3.y;
        }
        for (; t < cnt; t++) {
            int s = __shfl(sl, t, 64);
            float2 hv = *(const float2*)&h[(size_t)s * HDIM + c0];
            ax += hv.x; ay += hv.y;
        }
    }
    float2 o; o.x = ax; o.y = ay;
    *(float2*)&z[(size_t)node * HDIM + c0] = o;
}

// ---------------------------------------------------------------------------
// segment_sum (unchanged): sorted batch -> per-graph direct reduce
// ---------------------------------------------------------------------------
__global__ __launch_bounds__(128) void segsum2_kernel(const float* __restrict__ h,
                                                      const int* __restrict__ batch,
                                                      float* __restrict__ g) {
    int b = blockIdx.x;
    int tid = threadIdx.x;
    __shared__ int bounds[2];
    if (tid < 2) {
        int target = b + tid;
        int lo = 0, hi = N_NODES;
        while (lo < hi) {
            int mid = (lo + hi) >> 1;
            if (batch[mid] < target) lo = mid + 1; else hi = mid;
        }
        bounds[tid] = lo;
    }
    __syncthreads();
    int beg = bounds[0], end = bounds[1];
    float s = 0.f;
    for (int r = beg; r < end; r++) s += h[(size_t)r * HDIM + tid];
    g[b * HDIM + tid] = s;
}

// ---------------------------------------------------------------------------
// Weight prep, FRAG-MAJOR layout: flat index i = ((s*8+c)*64 + l)*8 + j where
// s=K-step, c=col-tile, l=lane(q=l>>4,c16=l&15), j=frag elem. Value =
// W[k][n] with n = c*16+c16, k = s*32+q*8+j. GEMM lane l reads its 16B frag
// for tile t at (t*64+l)*8 shorts — a wave's frag read is 1KB contiguous.
// ---------------------------------------------------------------------------
__device__ inline void dekker_split(float v, unsigned short& hi, unsigned short& lo) {
    unsigned u = __float_as_uint(v);
    hi = (unsigned short)(u >> 16);
    float flo = v - __uint_as_float(u & 0xffff0000u);
    lo = (unsigned short)(__float_as_uint(flo) >> 16);
}

__device__ inline void fragmajor_decode(int i, int& k, int& n) {
    int j = i & 7, l = (i >> 3) & 63, c = (i >> 9) & 7, s = (i >> 12) & 3;
    n = c * 16 + (l & 15);
    k = s * 32 + (l >> 4) * 8 + j;
}

__global__ __launch_bounds__(256) void prep_w(const float* __restrict__ W1,
                                              const float* __restrict__ W2,
                                              unsigned short* __restrict__ wh,
                                              unsigned short* __restrict__ wl) {
    int m = blockIdx.x;  // 0..5
    const float* src = (m < 3) ? (W1 + m * HDIM * HDIM) : (W2 + (m - 3) * HDIM * HDIM);
    unsigned short* dh = wh + m * HDIM * HDIM;
    unsigned short* dl = wl + m * HDIM * HDIM;
    for (int i = threadIdx.x; i < HDIM * HDIM; i += 256) {
        int k, n;
        fragmajor_decode(i, k, n);
        unsigned short h16, l16;
        dekker_split(src[k * HDIM + n], h16, l16);
        dh[i] = h16; dl[i] = l16;
    }
}

__global__ __launch_bounds__(256) void prep_feat(const float* __restrict__ W,
                                                 const float* __restrict__ bfeat,
                                                 const float* __restrict__ stats,
                                                 const float* __restrict__ gamma,
                                                 const float* __restrict__ beta,
                                                 float invCnt,
                                                 unsigned short* __restrict__ dh,
                                                 unsigned short* __restrict__ dl,
                                                 float* __restrict__ biasF) {
    __shared__ float aP[HDIM], bP[HDIM];
    int tid = threadIdx.x;
    if (tid < HDIM) {
        float m = stats[tid] * invCnt;
        float v = stats[HDIM + tid] * invCnt - m * m;
        float a = gamma[tid] * rsqrtf(v + BN_EPS);
        aP[tid] = a;
        bP[tid] = beta[tid] - m * a;
    }
    __syncthreads();
    for (int i = tid; i < HDIM * HDIM; i += 256) {
        int k, n;
        fragmajor_decode(i, k, n);
        unsigned short h16, l16;
        dekker_split(aP[k] * W[k * HDIM + n], h16, l16);
        dh[i] = h16; dl[i] = l16;
    }
    if (tid < HDIM) {
        float acc = bfeat[tid];
        for (int k = 0; k < HDIM; k++) acc = fmaf(bP[k], W[k * HDIM + tid], acc);
        biasF[tid] = acc;
    }
}

// ---------------------------------------------------------------------------
// MFMA GEMM v5 (B-in-registers, persistent grid-stride): C = op(A)@B + bias.
// bf16 Dekker 3-term (AhBh + AlBh + AhBl), fp32 accumulate — numerics
// identical to R7/v4 (same term/accumulation order).
// Post-mortem R11: every "stage B per block" variant (L2-serial, reg-ring,
// LDS) was latency-bound at <3% util — per-block serial chains + <=8 waves/CU
// left ~1 load in flight per wave. v5 inverts it: each wave loads its
// col-half of B ONCE into 128 VGPRs (frag-major -> 1KB-contiguous per frag),
// then grid-strides over row-tiles: 8 independent A float4 loads -> convert
// -> 48 MFMA -> coalesced 64B stores. Grid 512 = 2 blocks/CU; all 2048 waves
// resident; ~8KB A-loads in flight per wave. No B re-staging, LDS <= 1KB.
// MODE 0: plain A, RELU.  MODE 1: plain A, no relu, +STATS, in-place
// (per-iteration barrier: both col-half waves drain A reads before stores).
// MODE 2: BN+relu applied to A in-register (params from 1KB LDS table).
// ---------------------------------------------------------------------------
template <int MODE>
__global__ __launch_bounds__(256, 2) void mfma_gemm(const float* __restrict__ A,
                                                    const unsigned short* __restrict__ Bh,
                                                    const unsigned short* __restrict__ Bl,
                                                    const float* __restrict__ bias,
                                                    float* __restrict__ C,
                                                    const float* __restrict__ statsPre,
                                                    const float* __restrict__ gammaPre,
                                                    const float* __restrict__ betaPre,
                                                    float invCnt,
                                                    float* __restrict__ statsOut) {
    __shared__ float sA[HDIM], sBp[HDIM];  // MODE 2 BN params (1KB)
    const int tid = threadIdx.x;
    const int w = tid >> 6, l = tid & 63;
    const int q = l >> 4, c16 = l & 15;
    const int colHalf = w & 1, pairId = w >> 1;
    const int colBase = colHalf * 64;

    if (MODE == 2) {
        if (tid < HDIM) {
            float m = statsPre[tid] * invCnt;
            float var = statsPre[HDIM + tid] * invCnt - m * m;
            float a = gammaPre[tid] * rsqrtf(var + BN_EPS);
            sA[tid] = a;
            sBp[tid] = betaPre[tid] - m * a;
        }
        __syncthreads();
    }

    // B col-half fragments, held in registers for the whole kernel:
    // 32 x bf16x8 = 128 VGPRs, all statically indexed (full unroll).
    bf16x8 bh[4][4], bl[4][4];
#pragma unroll
    for (int s = 0; s < 4; s++)
#pragma unroll
        for (int cl = 0; cl < 4; cl++) {
            const size_t fo = ((size_t)(s * 8 + colHalf * 4 + cl) * 64 + l) * 8;
            bh[s][cl] = *(const bf16x8*)(Bh + fo);
            bl[s][cl] = *(const bf16x8*)(Bl + fo);
        }

    float bsv[4];
#pragma unroll
    for (int cl = 0; cl < 4; cl++) bsv[cl] = bias[colBase + cl * 16 + c16];

    float ssum[4], ssq[4];
    if (MODE == 1) {
#pragma unroll
        for (int cl = 0; cl < 4; cl++) { ssum[cl] = 0.f; ssq[cl] = 0.f; }
    }

    for (int it = 0; it < NITER; ++it) {
        const int tile = it * (GBLK * 2) + blockIdx.x * 2 + pairId;
        const bool live = tile < NTILES;
        const int tt = live ? tile : NTILES - 1;

        // 8 independent A float4 loads (16 rows x full K), wave-coalesced
        const float* ap = A + ((size_t)tt * 16 + c16) * HDIM + q * 8;
        float4 araw[4][2];
#pragma unroll
        for (int s = 0; s < 4; s++) {
            araw[s][0] = *(const float4*)(ap + s * 32);
            araw[s][1] = *(const float4*)(ap + s * 32 + 4);
        }

        f32x4 acc[4];
#pragma unroll
        for (int cl = 0; cl < 4; cl++) acc[cl] = (f32x4){0.f, 0.f, 0.f, 0.f};

#pragma unroll
        for (int s = 0; s < 4; s++) {
            const int k0 = s * 32 + q * 8;
            float vv[8] = {araw[s][0].x, araw[s][0].y, araw[s][0].z, araw[s][0].w,
                           araw[s][1].x, araw[s][1].y, araw[s][1].z, araw[s][1].w};
            bf16x8 ah, al;
#pragma unroll
            for (int j = 0; j < 8; j++) {
                float v = vv[j];
                if (MODE == 2) v = fmaxf(fmaf(v, sA[k0 + j], sBp[k0 + j]), 0.f);
                unsigned u = __float_as_uint(v);
                ah[j] = (short)(u >> 16);
                float flo = v - __uint_as_float(u & 0xffff0000u);
                al[j] = (short)(__float_as_uint(flo) >> 16);
            }
#pragma unroll
            for (int cl = 0; cl < 4; cl++) {
                f32x4 a0 = __builtin_amdgcn_mfma_f32_16x16x32_bf16(ah, bh[s][cl], acc[cl], 0, 0, 0);
                a0 = __builtin_amdgcn_mfma_f32_16x16x32_bf16(al, bh[s][cl], a0, 0, 0, 0);
                a0 = __builtin_amdgcn_mfma_f32_16x16x32_bf16(ah, bl[s][cl], a0, 0, 0, 0);
                acc[cl] = a0;
            }
        }

        // in-place (C==A) safety: the sibling col-half wave of this tile must
        // finish its A reads before we store. __syncthreads drains vmcnt.
        if (MODE == 1) __syncthreads();

        if (live) {
#pragma unroll
            for (int reg = 0; reg < 4; reg++) {
                float* cp = C + ((size_t)tt * 16 + q * 4 + reg) * HDIM + colBase + c16;
#pragma unroll
                for (int cl = 0; cl < 4; cl++) {
                    float v = acc[cl][reg] + bsv[cl];
                    if (MODE != 1) v = fmaxf(v, 0.f);
                    cp[cl * 16] = v;
                    if (MODE == 1) { ssum[cl] += v; ssq[cl] += v * v; }
                }
            }
        }
    }

    if (MODE == 1) {
#pragma unroll
        for (int cl = 0; cl < 4; cl++) {
            float s2 = ssum[cl] + __shfl_xor(ssum[cl], 16, 64);
            float s4 = s2 + __shfl_xor(s2, 32, 64);
            float t2 = ssq[cl] + __shfl_xor(ssq[cl], 16, 64);
            float t4 = t2 + __shfl_xor(t2, 32, 64);
            if (q == 0) {
                atomicAdd(&statsOut[colBase + cl * 16 + c16], s4);
                atomicAdd(&statsOut[HDIM + colBase + cl * 16 + c16], t4);
            }
        }
    }
}

// ---------------------------------------------------------------------------
// Small fp32 GEMM (kept for the 500-row FC block).
// ---------------------------------------------------------------------------
template <bool PRE_A, bool PRE_B, bool RELU, bool STATS>
__global__ __launch_bounds__(256, 3) void gemm_bn(const float* A, const float* __restrict__ B,
                                                  const float* __restrict__ bias, float* C, int M,
                                                  const float* __restrict__ statsPre,
                                                  const float* __restrict__ gammaPre,
                                                  const float* __restrict__ betaPre,
                                                  float invCnt, float* __restrict__ statsOut) {
    __shared__ float At[64][65];
    __shared__ float Bs[64][128];
    __shared__ float aPre[128], bPre[128];

    const int tid = threadIdx.x;
    const int tx = tid & 15, ty = tid >> 4;
    const int r0 = blockIdx.x * 64;

    if (PRE_A || PRE_B) {
        if (tid < 128) {
            float m = statsPre[tid] * invCnt;
            float v = statsPre[128 + tid] * invCnt - m * m;
            float a = gammaPre[tid] * rsqrtf(v + BN_EPS);
            aPre[tid] = a;
            bPre[tid] = betaPre[tid] - m * a;
        }
        __syncthreads();
    }

    float acc[4][8];
#pragma unroll
    for (int i = 0; i < 4; i++)
#pragma unroll
        for (int j = 0; j < 8; j++) acc[i][j] = 0.f;

    float biasEff[8];
#pragma unroll
    for (int j = 0; j < 8; j++) biasEff[j] = bias[8 * tx + j];
    if (PRE_B) {
        for (int k = 0; k < 128; k++) {
            float bb = bPre[k];
            const float* Brow = B + (size_t)k * HDIM + 8 * tx;
#pragma unroll
            for (int j = 0; j < 8; j++) biasEff[j] = fmaf(bb, Brow[j], biasEff[j]);
        }
    }

    for (int kc = 0; kc < 128; kc += 64) {
#pragma unroll
        for (int i = 0; i < 4; i++) {
            int f4 = tid + i * 256;
            int row = f4 >> 4;
            int kg = f4 & 15;
            int grow = r0 + row;
            float4 av;
            if (grow < M) av = *(const float4*)(A + (size_t)grow * HDIM + kc + kg * 4);
            else av = make_float4(0.f, 0.f, 0.f, 0.f);
            if (PRE_A) {
                int kb = kc + kg * 4;
                av.x = fmaxf(fmaf(av.x, aPre[kb + 0], bPre[kb + 0]), 0.f);
                av.y = fmaxf(fmaf(av.y, aPre[kb + 1], bPre[kb + 1]), 0.f);
                av.z = fmaxf(fmaf(av.z, aPre[kb + 2], bPre[kb + 2]), 0.f);
                av.w = fmaxf(fmaf(av.w, aPre[kb + 3], bPre[kb + 3]), 0.f);
            }
            At[kg * 4 + 0][row] = av.x;
            At[kg * 4 + 1][row] = av.y;
            At[kg * 4 + 2][row] = av.z;
            At[kg * 4 + 3][row] = av.w;
        }
#pragma unroll
        for (int i = 0; i < 8; i++) {
            int f4 = tid + i * 256;
            int krow = f4 >> 5;
            int cg = f4 & 31;
            float4 bv = *(const float4*)(B + (size_t)(kc + krow) * HDIM + cg * 4);
            if (PRE_B) {
                float s = aPre[kc + krow];
                bv.x *= s; bv.y *= s; bv.z *= s; bv.w *= s;
            }
            *(float4*)&Bs[krow][cg * 4] = bv;
        }
        __syncthreads();
#pragma unroll 8
        for (int k = 0; k < 64; k++) {
            float av[4];
            av[0] = At[k][ty];
            av[1] = At[k][ty + 16];
            av[2] = At[k][ty + 32];
            av[3] = At[k][ty + 48];
            const float4 b0 = *(const float4*)&Bs[k][8 * tx];
            const float4 b1 = *(const float4*)&Bs[k][8 * tx + 4];
            float bv[8] = {b0.x, b0.y, b0.z, b0.w, b1.x, b1.y, b1.z, b1.w};
#pragma unroll
            for (int i = 0; i < 4; i++)
#pragma unroll
                for (int j = 0; j < 8; j++) acc[i][j] = fmaf(av[i], bv[j], acc[i][j]);
        }
        __syncthreads();
    }

    float s[8], sq[8];
    if (STATS) {
#pragma unroll
        for (int j = 0; j < 8; j++) { s[j] = 0.f; sq[j] = 0.f; }
    }
#pragma unroll
    for (int i = 0; i < 4; i++) {
        int grow = r0 + ty + 16 * i;
        if (grow < M) {
            float v[8];
#pragma unroll
            for (int j = 0; j < 8; j++) {
                v[j] = acc[i][j] + biasEff[j];
                if (RELU) v[j] = fmaxf(v[j], 0.f);
                if (STATS) { s[j] += v[j]; sq[j] += v[j] * v[j]; }
            }
            float4 o0 = make_float4(v[0], v[1], v[2], v[3]);
            float4 o1 = make_float4(v[4], v[5], v[6], v[7]);
            *(float4*)(C + (size_t)grow * HDIM + 8 * tx) = o0;
            *(float4*)(C + (size_t)grow * HDIM + 8 * tx + 4) = o1;
        }
    }
    if (STATS) {
        float* red = &At[0][0];
#pragma unroll
        for (int j = 0; j < 8; j++) {
            red[ty * 128 + 8 * tx + j] = s[j];
            red[2048 + ty * 128 + 8 * tx + j] = sq[j];
        }
        __syncthreads();
        if (tid < 128) {
            float t = 0.f;
#pragma unroll
            for (int u = 0; u < 16; u++) t += red[u * 128 + tid];
            atomicAdd(&statsOut[tid], t);
        } else {
            int col = tid - 128;
            float t = 0.f;
#pragma unroll
            for (int u = 0; u < 16; u++) t += red[2048 + u * 128 + col];
            atomicAdd(&statsOut[128 + col], t);
        }
    }
}

// ---------------------------------------------------------------------------
// Head: logits = BN(g2)@W_cls + b_cls (BN folded), then log_softmax.
// ---------------------------------------------------------------------------
__global__ __launch_bounds__(256) void head_kernel(const float* __restrict__ g2,
                                                   const float* __restrict__ stats,
                                                   const float* __restrict__ gamma,
                                                   const float* __restrict__ beta,
                                                   const float* __restrict__ Wc,
                                                   const float* __restrict__ bc,
                                                   float* __restrict__ out, float invCnt) {
    __shared__ float Wf[HDIM * NCLS];
    __shared__ float bf[NCLS];
    __shared__ float aP[HDIM], bP[HDIM];
    const int tid = threadIdx.x;
    if (tid < HDIM) {
        float m = stats[tid] * invCnt;
        float v = stats[HDIM + tid] * invCnt - m * m;
        float a = gamma[tid] * rsqrtf(v + BN_EPS);
        aP[tid] = a;
        bP[tid] = beta[tid] - m * a;
    }
    __syncthreads();
    for (int idx = tid; idx < HDIM * NCLS; idx += 256) {
        int k = idx / NCLS;
        Wf[idx] = aP[k] * Wc[idx];
    }
    if (tid < NCLS) {
        float sv = bc[tid];
        for (int k = 0; k < HDIM; k++) sv = fmaf(bP[k], Wc[k * NCLS + tid], sv);
        bf[tid] = sv;
    }
    __syncthreads();
    int row = blockIdx.x * 256 + tid;
    if (row >= NGRAPH) return;
    float l[NCLS];
#pragma unroll
    for (int c = 0; c < NCLS; c++) l[c] = bf[c];
    for (int k = 0; k < HDIM; k++) {
        float gv = g2[row * HDIM + k];
#pragma unroll
        for (int c = 0; c < NCLS; c++) l[c] = fmaf(gv, Wf[k * NCLS + c], l[c]);
    }
    float mx = l[0];
#pragma unroll
    for (int c = 1; c < NCLS; c++) mx = fmaxf(mx, l[c]);
    float se = 0.f;
#pragma unroll
    for (int c = 0; c < NCLS; c++) se += expf(l[c] - mx);
    float lse = mx + logf(se);
#pragma unroll
    for (int c = 0; c < NCLS; c++) out[row * NCLS + c] = l[c] - lse;
}

// ---------------------------------------------------------------------------
extern "C" void kernel_launch(void* const* d_in, const int* in_sizes, int n_in,
                              void* d_out, int out_size, void* d_ws, size_t ws_size,
                              hipStream_t stream) {
    const float* x          = (const float*)d_in[0];
    const int*   ei         = (const int*)d_in[1];
    const int*   batch      = (const int*)d_in[2];
    const float* gamma_feat = (const float*)d_in[3];
    const float* beta_feat  = (const float*)d_in[4];
    const float* W_feat     = (const float*)d_in[5];
    const float* b_feat     = (const float*)d_in[6];
    const float* gin_W1     = (const float*)d_in[7];
    const float* gin_b1     = (const float*)d_in[8];
    const float* gin_gamma  = (const float*)d_in[9];
    const float* gin_beta   = (const float*)d_in[10];
    const float* gin_W2     = (const float*)d_in[11];
    const float* gin_b2     = (const float*)d_in[12];
    const float* gamma_fc   = (const float*)d_in[13];
    const float* beta_fc    = (const float*)d_in[14];
    const float* W_fc       = (const float*)d_in[15];
    const float* b_fc       = (const float*)d_in[16];
    const float* gamma_h    = (const float*)d_in[17];
    const float* beta_h     = (const float*)d_in[18];
    const float* W_cls      = (const float*)d_in[19];
    const float* b_cls      = (const float*)d_in[20];
    float* out = (float*)d_out;

    float* ws = (float*)d_ws;
    size_t off = 0;
    float* h  = ws + off; off += (size_t)N_NODES * HDIM;
    float* zy = ws + off; off += (size_t)N_NODES * HDIM;   // z and y alias (in-place mode-1 gemm)
    float* g2 = ws + off; off += NGRAPH * HDIM;
    float* g  = ws + off; off += NGRAPH * HDIM;            // fully written by segsum2
    size_t zstart = off;                                    // ---- zeroed region ----
    float* stats = ws + off; off += 256 * 6;
    int* counts = (int*)(ws + off); off += N_NODES;
    size_t zbytes = (off - zstart) * sizeof(float);         // ---- end zeroed ----
    int* offsets   = (int*)(ws + off); off += N_NODES + 1;
    int* cursor    = (int*)(ws + off); off += N_NODES;
    int* csr       = (int*)(ws + off); off += N_EDGES;
    int* partial   = (int*)(ws + off); off += N_NODES;
    int* blockSums = (int*)(ws + off); off += 256;
    int* blockBase = (int*)(ws + off); off += 256;
    off = (off + 3) & ~(size_t)3;                           // 16B-align weight arrays
    unsigned short* wt_hi = (unsigned short*)(ws + off); off += 7 * HDIM * HDIM / 2;
    unsigned short* wt_lo = (unsigned short*)(ws + off); off += 7 * HDIM * HDIM / 2;
    float* biasF = ws + off; off += HDIM;

    float* statsX  = stats;
    float* statsYa[3] = {stats + 256, stats + 512, stats + 768};
    float* statsG  = stats + 1024;
    float* statsG2 = stats + 1280;

    hipMemsetAsync(stats, 0, zbytes, stream);

    const float invN = 1.f / (float)N_NODES;
    const float invG = 1.f / (float)NGRAPH;
    const int eblocks = (N_EDGES + 255) / 256;        // 2344
    const int nwaves  = (N_NODES * 64 + 255) / 256;   // 12500

    // GIN weight prep (no deps) + BN(x) stats + CSR build
    prep_w<<<6, 256, 0, stream>>>(gin_W1, gin_W2, wt_hi, wt_lo);
    colstats_kernel<<<256, 256, 0, stream>>>(x, N_NODES, statsX);
    hist_kernel<<<eblocks, 256, 0, stream>>>(ei, counts);
    scan1_kernel<<<SCAN_BLOCKS, 256, 0, stream>>>(counts, partial, blockSums);
    scan2_kernel<<<1, 256, 0, stream>>>(blockSums, blockBase);
    scan3_kernel<<<SCAN_BLOCKS, 256, 0, stream>>>(partial, blockBase, offsets, cursor);
    fill_kernel<<<eblocks, 256, 0, stream>>>(ei, cursor, csr);
    prep_feat<<<1, 256, 0, stream>>>(W_feat, b_feat, statsX, gamma_feat, beta_feat, invN,
                                     wt_hi + 6 * HDIM * HDIM, wt_lo + 6 * HDIM * HDIM, biasF);

    // h = relu(BN(x) @ W_feat + b_feat)   [BN folded into prepped B]
    mfma_gemm<0><<<GBLK, 256, 0, stream>>>(
        x, wt_hi + 6 * HDIM * HDIM, wt_lo + 6 * HDIM * HDIM, biasF, h,
        nullptr, nullptr, nullptr, invN, nullptr);

    for (int i = 0; i < 3; i++) {
        // z = h + sum_neighbors h
        agg_kernel<<<nwaves, 256, 0, stream>>>(h, offsets, csr, zy);
        // y = z @ W1 + b1   (in-place, + column stats of y)
        mfma_gemm<1><<<GBLK, 256, 0, stream>>>(
            zy, wt_hi + i * HDIM * HDIM, wt_lo + i * HDIM * HDIM, gin_b1 + i * HDIM,
            zy, nullptr, nullptr, nullptr, invN, statsYa[i]);
        // h = relu( relu(BN(y)) @ W2 + b2 )   [BN+relu in-register on A frags]
        mfma_gemm<2><<<GBLK, 256, 0, stream>>>(
            zy, wt_hi + (3 + i) * HDIM * HDIM, wt_lo + (3 + i) * HDIM * HDIM, gin_b2 + i * HDIM,
            h, statsYa[i], gin_gamma + i * HDIM, gin_beta + i * HDIM, invN, nullptr);
    }

    // g = segment_sum(h, batch)  (sorted batch -> direct per-graph reduce)
    segsum2_kernel<<<NGRAPH, 128, 0, stream>>>(h, batch, g);
    colstats_kernel<<<8, 256, 0, stream>>>(g, NGRAPH, statsG);
    // g2 = relu(BN(g) @ W_fc + b_fc) + stats of g2
    gemm_bn<false, true, true, true><<<(NGRAPH + 63) / 64, 256, 0, stream>>>(
        g, W_fc, b_fc, g2, NGRAPH, statsG, gamma_fc, beta_fc, invG, statsG2);
    // logits = BN(g2) @ W_cls + b_cls -> log_softmax
    head_kernel<<<2, 256, 0, stream>>>(g2, statsG2, gamma_h, beta_h, W_cls, b_cls, out, invG);
}